// Round 2
// baseline (464.723 us; speedup 1.0000x reference)
//
#include <hip/hip_runtime.h>

#define BETA 0.9f
#define THRESH 1.0f

constexpr int Bsz  = 64;
constexpr int Din  = 1024;
constexpr int Dout = 1024;
constexpr int NBJ  = Bsz * Dout;   // 65536 elements of [B, Dout]

// ---------------------------------------------------------------------------
// A: fused GEMM + LIF.  One block = (b, jc) covering 256 columns, 512 threads.
//    tid = kh*256 + jl :  kh in {0,1} is the K-half, jl is the local column.
//    Each thread accumulates a half-K dot product; LDS reduce; then threads
//    0..255 run the LIF elementwise math and write spk/u/E_b/one_m.
//    x[b,k] is wave-uniform -> scalar loads; W[k*Dout+j] coalesced.
// ---------------------------------------------------------------------------
__global__ __launch_bounds__(512) void gemm_lif(const float* __restrict__ x,
                                                const float* __restrict__ W,
                                                const float* __restrict__ bias,
                                                const float* __restrict__ u0,
                                                const float* __restrict__ E_b,
                                                float* __restrict__ out_spk,
                                                float* __restrict__ out_u,
                                                float* __restrict__ out_Eb,
                                                float* __restrict__ one_m_ws) {
    __shared__ float red[512];

    int blk = blockIdx.x;            // 0..255
    int b   = blk >> 2;              // 0..63
    int jc  = blk & 3;               // 0..3
    int jl  = threadIdx.x & 255;     // local column
    int kh  = threadIdx.x >> 8;      // K-half
    int j   = (jc << 8) + jl;

    const float* xr = x + b * Din + kh * 512;           // wave-uniform
    const float* Wc = W + (size_t)(kh * 512) * Dout + j;

    float acc = 0.f;
#pragma unroll 16
    for (int k = 0; k < 512; ++k) {
        acc = fmaf(xr[k], Wc[(size_t)k * Dout], acc);
    }
    red[threadIdx.x] = acc;
    __syncthreads();

    if (threadIdx.x < 256) {
        int   idx = b * Dout + j;
        float I   = red[threadIdx.x] + red[threadIdx.x + 256] + bias[j];
        float v   = fmaf(BETA, u0[idx], I);
        float vt  = v - THRESH;
        float spk = vt > 0.f ? 1.f : 0.f;
        float a   = 1.f + fabsf(vt);
        float sg  = 1.f / (a * a);
        float om  = 1.f - THRESH * sg;          // one_m = d u_new / d v

        out_spk[idx]  = spk;
        out_u[idx]    = v - THRESH * spk;
        // E_b_new = BETA*one_m*E_b + one_m = one_m*(BETA*E_b + 1)
        out_Eb[idx]   = om * fmaf(BETA, E_b[idx], 1.f);
        one_m_ws[idx] = om;
    }
}

// ---------------------------------------------------------------------------
// B: the big stream.  E_W_new[b,i,j] = one_m[b,j] * (BETA*E_W[b,i,j] + x[b,i])
//    One block = 4 consecutive rows (same b): one_m float4 loaded ONCE and
//    reused; 4 independent float4 load/store pairs per thread for MLP.
//    512 MB HBM traffic — this is the roofline term (~81 µs @ 6.3 TB/s).
// ---------------------------------------------------------------------------
__global__ __launch_bounds__(256) void ew_update(const float4* __restrict__ E_W,
                                                 const float*  __restrict__ x,
                                                 const float4* __restrict__ one_m,
                                                 float4* __restrict__ out_EW) {
    unsigned blk = blockIdx.x;       // 0..16383
    unsigned b   = blk >> 8;         // sample
    unsigned i0  = (blk & 255u) << 2;   // first of 4 rows
    unsigned jv  = threadIdx.x;      // float4 column 0..255

    float4 om = one_m[(b << 8) + jv];

    size_t base = ((size_t)b * Din + i0) * 256 + jv;   // float4 units
    const float* xb = x + b * Din + i0;                // wave-uniform scalars

    float  xs0 = xb[0], xs1 = xb[1], xs2 = xb[2], xs3 = xb[3];
    float4 e0 = E_W[base];
    float4 e1 = E_W[base + 256];
    float4 e2 = E_W[base + 512];
    float4 e3 = E_W[base + 768];

    float4 r;
    r.x = om.x * fmaf(BETA, e0.x, xs0);
    r.y = om.y * fmaf(BETA, e0.y, xs0);
    r.z = om.z * fmaf(BETA, e0.z, xs0);
    r.w = om.w * fmaf(BETA, e0.w, xs0);
    out_EW[base] = r;
    r.x = om.x * fmaf(BETA, e1.x, xs1);
    r.y = om.y * fmaf(BETA, e1.y, xs1);
    r.z = om.z * fmaf(BETA, e1.z, xs1);
    r.w = om.w * fmaf(BETA, e1.w, xs1);
    out_EW[base + 256] = r;
    r.x = om.x * fmaf(BETA, e2.x, xs2);
    r.y = om.y * fmaf(BETA, e2.y, xs2);
    r.z = om.z * fmaf(BETA, e2.z, xs2);
    r.w = om.w * fmaf(BETA, e2.w, xs2);
    out_EW[base + 512] = r;
    r.x = om.x * fmaf(BETA, e3.x, xs3);
    r.y = om.y * fmaf(BETA, e3.y, xs3);
    r.z = om.z * fmaf(BETA, e3.z, xs3);
    r.w = om.w * fmaf(BETA, e3.w, xs3);
    out_EW[base + 768] = r;
}

extern "C" void kernel_launch(void* const* d_in, const int* in_sizes, int n_in,
                              void* d_out, int out_size, void* d_ws, size_t ws_size,
                              hipStream_t stream) {
    const float* x    = (const float*)d_in[0];
    const float* W    = (const float*)d_in[1];
    const float* bias = (const float*)d_in[2];
    const float* u0   = (const float*)d_in[3];
    const float* E_W  = (const float*)d_in[4];
    const float* E_b  = (const float*)d_in[5];

    float* out     = (float*)d_out;
    float* out_spk = out;                       // [64,1024]
    float* out_u   = out + NBJ;                 // [64,1024]
    float* out_EW  = out + 2 * NBJ;             // [64,1024,1024]
    float* out_Eb  = out + 2 * NBJ + (size_t)Bsz * Din * Dout;  // [64,1024]

    float* one_m = (float*)d_ws;                // 65536 floats = 256 KB

    gemm_lif<<<Bsz * (Dout / 256), 512, 0, stream>>>(x, W, bias, u0, E_b,
                                                     out_spk, out_u, out_Eb, one_m);
    ew_update<<<Bsz * (Din / 4), 256, 0, stream>>>((const float4*)E_W, x,
                                                   (const float4*)one_m,
                                                   (float4*)out_EW);
}